// Round 2
// baseline (8883.456 us; speedup 1.0000x reference)
//
#include <hip/hip_runtime.h>
#include <hip/hip_bf16.h>
#include <stdint.h>

// ---------------------------------------------------------------------------
// Tacotron2 decoder on MI355X — persistent pipelined recurrence, v8.
// v8 = v7 with the role-1/3 P-gate prefetch converted to ISSUE-ONLY: the 4
// gate loads go in flight with NO waitcnt and drain under the h-ring
// ld8_mall's vmcnt(0) (one MALL round trip covers both, instead of two
// serialized RTs). The consume site pins the registers with an inout
// s_waitcnt vmcnt(0) + sched_barrier(0) (free there: the LDS-reduction
// __syncthreads already drained vmcnt). Saves ~1 MALL RT/tick on the
// role-1/3 critical path. Everything else identical to v7 (9279.2 us).
// ---------------------------------------------------------------------------

typedef short  bf16x8  __attribute__((ext_vector_type(8)));
typedef float  f32x16  __attribute__((ext_vector_type(16)));

// ---------------- threefry2x32 (exact JAX semantics) ------------------------
__device__ __forceinline__ uint32_t rotl32(uint32_t x, int r) {
  return (x << r) | (x >> (32 - r));
}

__device__ __forceinline__ void tf2x32(uint32_t k0, uint32_t k1,
                                       uint32_t x0, uint32_t x1,
                                       uint32_t& o0, uint32_t& o1) {
  uint32_t k2 = k0 ^ k1 ^ 0x1BD11BDAu;
  x0 += k0; x1 += k1;
#define TF_R(r) { x0 += x1; x1 = rotl32(x1, r); x1 ^= x0; }
  TF_R(13) TF_R(15) TF_R(26) TF_R(6)   x0 += k1; x1 += k2 + 1u;
  TF_R(17) TF_R(29) TF_R(16) TF_R(24)  x0 += k2; x1 += k0 + 2u;
  TF_R(13) TF_R(15) TF_R(26) TF_R(6)   x0 += k0; x1 += k1 + 3u;
  TF_R(17) TF_R(29) TF_R(16) TF_R(24)  x0 += k1; x1 += k2 + 4u;
  TF_R(13) TF_R(15) TF_R(26) TF_R(6)   x0 += k2; x1 += k0 + 5u;
#undef TF_R
  o0 = x0; o1 = x1;
}

__device__ __forceinline__ void dropout_keys(uint32_t& a1, uint32_t& b1,
                                             uint32_t& a2, uint32_t& b2) {
  uint32_t o0, o1, p0, p1;
  tf2x32(0u, 42u, 0u, 2u, o0, o1);
  tf2x32(0u, 42u, 1u, 3u, p0, p1);
  a1 = o0; b1 = p0;
  a2 = o1; b2 = p1;
}

__device__ __forceinline__ bool keep_mask(uint32_t ka, uint32_t kb, uint32_t e) {
  const uint32_t H = 4923392u;       // (601*64*256)/2
  uint32_t o0, o1;
  if (e < H) { tf2x32(ka, kb, e, e + H, o0, o1); return o0 < 0x80000000u; }
  else       { tf2x32(ka, kb, e - H, e, o0, o1); return o1 < 0x80000000u; }
}

__device__ __forceinline__ float sigf(float x)  { return 1.f / (1.f + __expf(-x)); }
__device__ __forceinline__ float tanhf2(float x){ return 2.f / (1.f + __expf(-2.f * x)) - 1.f; }

__device__ __forceinline__ short bf16bits(float f) {
  __hip_bfloat16 h = __float2bfloat16(f);
  short s; __builtin_memcpy(&s, &h, 2);
  return s;
}
__device__ __forceinline__ float bflo(uint32_t u) {
  uint32_t x = u << 16; float f; __builtin_memcpy(&f, &x, 4); return f;
}
__device__ __forceinline__ float bfhi(uint32_t u) {
  uint32_t x = u & 0xffff0000u; float f; __builtin_memcpy(&f, &x, 4); return f;
}

// ---- relaxed agent-scope single-word accessors (flags only) ----------------
__device__ __forceinline__ void st_u32_a(void* p, uint32_t v) {
  __hip_atomic_store((uint32_t*)p, v, __ATOMIC_RELAXED, __HIP_MEMORY_SCOPE_AGENT);
}

// ---- BATCHED MALL loads: sc0 sc1 = bypass L1+L2, served at coherent MALL.
// N loads in flight, ONE s_waitcnt — ~1 round trip instead of N. -------------
__device__ __forceinline__ void ld8_mall(const __hip_bfloat16* p, bf16x8 (&d)[8]) {
  asm volatile(
      "global_load_dwordx4 %0, %8, off sc0 sc1\n\t"
      "global_load_dwordx4 %1, %8, off offset:32 sc0 sc1\n\t"
      "global_load_dwordx4 %2, %8, off offset:64 sc0 sc1\n\t"
      "global_load_dwordx4 %3, %8, off offset:96 sc0 sc1\n\t"
      "global_load_dwordx4 %4, %8, off offset:128 sc0 sc1\n\t"
      "global_load_dwordx4 %5, %8, off offset:160 sc0 sc1\n\t"
      "global_load_dwordx4 %6, %8, off offset:192 sc0 sc1\n\t"
      "global_load_dwordx4 %7, %8, off offset:224 sc0 sc1\n\t"
      "s_waitcnt vmcnt(0)"
      : "=&v"(d[0]), "=&v"(d[1]), "=&v"(d[2]), "=&v"(d[3]),
        "=&v"(d[4]), "=&v"(d[5]), "=&v"(d[6]), "=&v"(d[7])
      : "v"(p) : "memory");
}
// 4 independent addresses, ISSUE ONLY (no waitcnt): used for the role-1/3
// P-gate prefetch. The loads drain under the next ld8_mall's vmcnt(0) /
// the reduction barriers; consumer must pin with ld4_pin() first.
__device__ __forceinline__ void ld4_mall4_issue(const uint32_t* p0, const uint32_t* p1,
                                                const uint32_t* p2, const uint32_t* p3,
                                                uint32_t (&d)[4]) {
  asm volatile(
      "global_load_dword %0, %4, off sc0 sc1\n\t"
      "global_load_dword %1, %5, off sc0 sc1\n\t"
      "global_load_dword %2, %6, off sc0 sc1\n\t"
      "global_load_dword %3, %7, off sc0 sc1"
      : "=&v"(d[0]), "=&v"(d[1]), "=&v"(d[2]), "=&v"(d[3])
      : "v"(p0), "v"(p1), "v"(p2), "v"(p3) : "memory");
}
// redefine the 4 regs behind a vmcnt drain so no use can be hoisted above it
__device__ __forceinline__ void ld4_pin(uint32_t (&d)[4]) {
  asm volatile("s_waitcnt vmcnt(0)"
               : "+v"(d[0]), "+v"(d[1]), "+v"(d[2]), "+v"(d[3])
               :: "memory");
  __builtin_amdgcn_sched_barrier(0);
}
// 4 dwords at +0,+512,+1024,+1536 bytes (proj h2 rows)
__device__ __forceinline__ void ld4_mall_s512(const __hip_bfloat16* p,
                                              uint32_t (&d)[4]) {
  asm volatile(
      "global_load_dword %0, %4, off sc0 sc1\n\t"
      "global_load_dword %1, %4, off offset:512 sc0 sc1\n\t"
      "global_load_dword %2, %4, off offset:1024 sc0 sc1\n\t"
      "global_load_dword %3, %4, off offset:1536 sc0 sc1\n\t"
      "s_waitcnt vmcnt(0)"
      : "=&v"(d[0]), "=&v"(d[1]), "=&v"(d[2]), "=&v"(d[3])
      : "v"(p) : "memory");
}
// barrier poll: 4 dwords at +0,+256,+512,+768 bytes
__device__ __forceinline__ void ld4_flags(const uint32_t* p, uint32_t (&d)[4]) {
  asm volatile(
      "global_load_dword %0, %4, off sc0 sc1\n\t"
      "global_load_dword %1, %4, off offset:256 sc0 sc1\n\t"
      "global_load_dword %2, %4, off offset:512 sc0 sc1\n\t"
      "global_load_dword %3, %4, off offset:768 sc0 sc1\n\t"
      "s_waitcnt vmcnt(0)"
      : "=&v"(d[0]), "=&v"(d[1]), "=&v"(d[2]), "=&v"(d[3])
      : "v"(p) : "memory");
}

// ---------------- prenet layer 1 --------------------------------------------
__global__ void prenet1_kernel(const float* __restrict__ dec,
                               const float* __restrict__ Wp1,
                               float* __restrict__ pn1) {
  const int t = blockIdx.x;
  const int tid = threadIdx.x;
  __shared__ float          sdec[64][81];
  __shared__ __hip_bfloat16 sw1[256][80];
  for (int idx = tid; idx < 64 * 80; idx += 256) {
    int b = idx / 80, m = idx - b * 80;
    sdec[b][m] = (t == 0) ? 0.f : dec[b * 48000 + m * 600 + (t - 1)];
  }
  for (int idx = tid; idx < 256 * 80; idx += 256) {
    int j = idx / 80, k = idx - j * 80;
    sw1[j][k] = __float2bfloat16(Wp1[idx]);
  }
  __syncthreads();
  uint32_t ka, kb, ka2, kb2;
  dropout_keys(ka, kb, ka2, kb2);
  const int b  = tid & 63;
  const int jg = tid >> 6;
  for (int jj = 0; jj < 64; ++jj) {
    const int j = jg * 64 + jj;
    float acc = 0.f;
    #pragma unroll
    for (int k = 0; k < 80; ++k)
      acc += sdec[b][k] * __bfloat162float(sw1[j][k]);
    const uint32_t e = (uint32_t)((t * 64 + b) * 256 + j);
    pn1[(t * 64 + b) * 256 + j] =
        keep_mask(ka, kb, e) ? 2.f * fmaxf(acc, 0.f) : 0.f;
  }
}

// ---------------- prenet layer 2 -> X[t][b][0..255] (bf16) ------------------
__global__ void prenet2_kernel(const float* __restrict__ pn1,
                               const float* __restrict__ Wp2,
                               __hip_bfloat16* __restrict__ X) {
  const int t  = blockIdx.x;
  const int j0 = blockIdx.y * 32;
  const int tid = threadIdx.x;
  __shared__ __hip_bfloat16 sact[64][258];
  __shared__ __hip_bfloat16 sw[32][256];
  for (int idx = tid; idx < 64 * 256; idx += 256) {
    int b = idx >> 8, k = idx & 255;
    sact[b][k] = __float2bfloat16(pn1[(t * 64 + b) * 256 + k]);
  }
  for (int idx = tid; idx < 32 * 256; idx += 256) {
    int r = idx >> 8, k = idx & 255;
    sw[r][k] = __float2bfloat16(Wp2[(j0 + r) * 256 + k]);
  }
  __syncthreads();
  uint32_t ka, kb, ka2, kb2;
  dropout_keys(ka, kb, ka2, kb2);
  const int b  = tid & 63;
  const int jg = tid >> 6;
  float acc[8];
  #pragma unroll
  for (int c = 0; c < 8; ++c) acc[c] = 0.f;
  for (int k = 0; k < 256; ++k) {
    const float a = __bfloat162float(sact[b][k]);
    #pragma unroll
    for (int c = 0; c < 8; ++c)
      acc[c] += a * __bfloat162float(sw[jg * 8 + c][k]);
  }
  #pragma unroll
  for (int c = 0; c < 8; ++c) {
    const int j = j0 + jg * 8 + c;
    const uint32_t e = (uint32_t)((t * 64 + b) * 256 + j);
    const float v = keep_mask(ka2, kb2, e) ? 2.f * fmaxf(acc[c], 0.f) : 0.f;
    X[(t * 64 + b) * 1024 + j] = __float2bfloat16(v);
  }
}

// ---------------- X[t][b][256..799] = dur[b][t][:], [800..1023] = 0 ---------
__global__ void xfill_kernel(const float* __restrict__ dur,
                             __hip_bfloat16* __restrict__ X) {
  const int idx = blockIdx.x * 256 + threadIdx.x;
  const int t  = idx / 49152;
  const int r  = idx - t * 49152;
  const int b  = r / 768;
  const int kk = r - b * 768;
  const float v = (kk < 544) ? dur[(b * 600 + t) * 544 + kk] : 0.f;
  X[(t * 64 + b) * 1024 + 256 + kk] = __float2bfloat16(v);
}

__global__ void wprojcvt_kernel(const float* __restrict__ W,
                                __hip_bfloat16* __restrict__ Wb) {
  const int idx = blockIdx.x * 256 + threadIdx.x;
  Wb[idx] = __float2bfloat16(W[idx]);
}

// ---------------- persistent pipelined recurrence ---------------------------
__launch_bounds__(512, 2)
__global__ void persist_kernel(
    const float* __restrict__ Wih1, const float* __restrict__ Whh1,
    const float* __restrict__ bih1, const float* __restrict__ bhh1,
    const float* __restrict__ Wih2, const float* __restrict__ Whh2,
    const float* __restrict__ bih2, const float* __restrict__ bhh2,
    const __hip_bfloat16* __restrict__ WprojB, const float* __restrict__ bproj,
    const __hip_bfloat16* __restrict__ Xbuf,
    uint32_t* __restrict__ P0, uint32_t* __restrict__ P1,     // bf16-pair rings
    __hip_bfloat16* __restrict__ h1buf, __hip_bfloat16* __restrict__ h2buf,
    uint32_t* __restrict__ flags,
    float* __restrict__ out) {
  const int bid  = blockIdx.x;
  const int role = bid >> 6;          // 0:AX 1:AF 2:B1 3:BF
  const int sub  = bid & 63;
  const int tid  = threadIdx.x;
  const int wave = tid >> 6;          // 8 waves
  const int lane = tid & 63;
  const int mh   = wave & 1;          // batch half
  const int kseg = wave >> 1;         // K quarter (256)

  __shared__ float pbuf[2][32][64];   // reduced gates [mh][m][n]
  __shared__ float sbuf[8][8];        // proj cross-wave partials

  // ---- persistent weight fragments (bf16, MFMA B layout) ----
  const float* Wsrc = (role == 0) ? Wih1 : (role == 1) ? Whh1
                    : (role == 2) ? Wih2 : Whh2;
  const int Ksrc  = (role == 0) ? 800 : 1024;
  const int nrow  = lane & 31;
  const int khalf = (lane >> 5) * 8;
  bf16x8 bfr[16][2];
  #pragma unroll
  for (int ks = 0; ks < 16; ++ks) {
    #pragma unroll
    for (int nt = 0; nt < 2; ++nt) {
      const int nloc = nt * 32 + nrow;
      const int g = (role == 1 || role == 3)
                  ? ((nloc >> 4) * 1024 + sub * 16 + (nloc & 15))  // i/f/g/o interleave
                  : (sub * 64 + nloc);                             // natural slice
      const int k0 = kseg * 256 + ks * 16 + khalf;
      bf16x8 v;
      if (k0 + 8 <= Ksrc) {
        const float* wp = Wsrc + (size_t)g * (size_t)Ksrc + k0;
        #pragma unroll
        for (int j = 0; j < 8; ++j) v[j] = bf16bits(wp[j]);
      } else {
        #pragma unroll
        for (int j = 0; j < 8; ++j) v[j] = (short)0;
      }
      bfr[ks][nt] = v;
    }
  }

  // ---- bias registers (role 0/2 write path): 8 consecutive gate cols ------
  float breg[8];
  if (role == 0 || role == 2) {
    const float* bi = (role == 0) ? bih1 : bih2;
    const float* bh = (role == 0) ? bhh1 : bhh2;
    const int c0 = (tid * 8) & 63;
    #pragma unroll
    for (int j = 0; j < 8; ++j) {
      const int g = sub * 64 + c0 + j;
      breg[j] = bi[g] + bh[g];
    }
  }

  float cst[2] = {0.f, 0.f};          // c-state: (b = tid>>3, cols hcp, hcp+1)
  const int brow = mh * 32 + (lane & 31);

  for (int tau = 0; tau < 604; ++tau) {
    const int sl = tau & 1;
    const bool active =
        (role == 0) ? (tau <= 599) :
        (role == 1) ? (tau >= 1 && tau <= 600) :
        (role == 2) ? (tau >= 2 && tau <= 601) :
                      (tau >= 3 && tau <= 602);
    f32x16 acc0, acc1;
    #pragma unroll
    for (int i = 0; i < 16; ++i) { acc0[i] = 0.f; acc1[i] = 0.f; }

    uint32_t pg4[4] = {0u, 0u, 0u, 0u};   // prefetched P gate pairs (roles 1/3)

    if (active) {
      if (role == 0) {
        // X is read-only input: plain cached loads
        const bf16x8* ap = reinterpret_cast<const bf16x8*>(
            Xbuf + (size_t)tau * 65536 + brow * 1024 + kseg * 256 + khalf);
        #pragma unroll
        for (int ks = 0; ks < 16; ++ks) {
          const bf16x8 a = ap[ks * 2];
          acc0 = __builtin_amdgcn_mfma_f32_32x32x16_bf16(a, bfr[ks][0], acc0, 0, 0, 0);
          acc1 = __builtin_amdgcn_mfma_f32_32x32x16_bf16(a, bfr[ks][1], acc1, 0, 0, 0);
        }
      } else {
        // P-gate prefetch (roles 1/3): ISSUE ONLY — drains under the h-ring
        // ld8_mall vmcnt(0) below, so it costs no extra MALL round trip.
        if (role & 1) {
          const uint32_t* Psrc = ((role == 1) ? P0 : P1) + ((tau + 1) & 1) * 131072;
          const int hcp = (tid & 7) * 2;
          const int pb  = tid >> 3;
          const uint32_t* q = Psrc + ((pb * 4096 + sub * 16 + hcp) >> 1);
          ld4_mall4_issue(q, q + 512, q + 1024, q + 1536, pg4);
        }
        // h ring (cross-block comm) — two 8-load batches from MALL
        const __hip_bfloat16* Asrc =
            ((role == 3) ? h2buf : h1buf) + sl * 65536;
        const __hip_bfloat16* abase = Asrc + brow * 1024 + kseg * 256 + khalf;
        bf16x8 A[8];
        ld8_mall(abase, A);
        #pragma unroll
        for (int ks = 0; ks < 8; ++ks) {
          acc0 = __builtin_amdgcn_mfma_f32_32x32x16_bf16(A[ks], bfr[ks][0], acc0, 0, 0, 0);
          acc1 = __builtin_amdgcn_mfma_f32_32x32x16_bf16(A[ks], bfr[ks][1], acc1, 0, 0, 0);
        }
        ld8_mall(abase + 128, A);   // +256 B: ks 8..15
        #pragma unroll
        for (int ks = 0; ks < 8; ++ks) {
          acc0 = __builtin_amdgcn_mfma_f32_32x32x16_bf16(A[ks], bfr[ks + 8][0], acc0, 0, 0, 0);
          acc1 = __builtin_amdgcn_mfma_f32_32x32x16_bf16(A[ks], bfr[ks + 8][1], acc1, 0, 0, 0);
        }
      }
    }
    // ---- K-split partial reduction through LDS (4 rounds) ----
    #pragma unroll
    for (int r = 0; r < 4; ++r) {
      if (active && kseg == r) {
        #pragma unroll
        for (int reg = 0; reg < 16; ++reg) {
          const int mrow = (reg & 3) + 8 * (reg >> 2) + 4 * (lane >> 5);
          const int col  = lane & 31;
          if (r == 0) {
            pbuf[mh][mrow][col]      = acc0[reg];
            pbuf[mh][mrow][col + 32] = acc1[reg];
          } else {
            pbuf[mh][mrow][col]      += acc0[reg];
            pbuf[mh][mrow][col + 32] += acc1[reg];
          }
        }
      }
      __syncthreads();
    }
    // ---- consume ----
    if (active) {
      if (role == 0 || role == 2) {   // write P ring (bf16 pairs, bypass)
        uint32_t* Pd = ((role == 0) ? P0 : P1) + sl * 131072;
        const int i0 = tid * 8;
        const int b  = i0 >> 6;
        const int c0 = i0 & 63;
        uint32_t* dst = Pd + ((b * 4096 + sub * 64 + c0) >> 1);
        const float* pr = &pbuf[b >> 5][b & 31][0];
        #pragma unroll
        for (int j = 0; j < 4; ++j) {
          const uint32_t lo = (uint32_t)(uint16_t)bf16bits(pr[c0 + 2 * j]     + breg[2 * j]);
          const uint32_t hi = (uint32_t)(uint16_t)bf16bits(pr[c0 + 2 * j + 1] + breg[2 * j + 1]);
          st_u32_a(dst + j, lo | (hi << 16));
        }
      } else {                        // LSTM pointwise with prefetched gates
        // pin: pg4 regs only valid after vmcnt drain. The reduction-round
        // __syncthreads already drained vmcnt, so this wait is free — it
        // exists to stop the compiler hoisting pg4 uses above the drain.
        ld4_pin(pg4);
        __hip_bfloat16* hdst =
            ((role == 1) ? h1buf : h2buf) + ((tau + 1) & 1) * 65536;
        const int hcp = (tid & 7) * 2;
        const int b   = tid >> 3;
        const float* pr = &pbuf[b >> 5][b & 31][0];
        const float gi0 = pr[hcp]      + bflo(pg4[0]), gi1 = pr[hcp + 1]      + bfhi(pg4[0]);
        const float gf0 = pr[16 + hcp] + bflo(pg4[1]), gf1 = pr[16 + hcp + 1] + bfhi(pg4[1]);
        const float gg0 = pr[32 + hcp] + bflo(pg4[2]), gg1 = pr[32 + hcp + 1] + bfhi(pg4[2]);
        const float go0 = pr[48 + hcp] + bflo(pg4[3]), go1 = pr[48 + hcp + 1] + bfhi(pg4[3]);
        const float c0n = sigf(gf0) * cst[0] + sigf(gi0) * tanhf2(gg0);
        const float c1n = sigf(gf1) * cst[1] + sigf(gi1) * tanhf2(gg1);
        cst[0] = c0n; cst[1] = c1n;
        const uint32_t h0 = (uint32_t)(uint16_t)bf16bits(sigf(go0) * tanhf2(c0n));
        const uint32_t h1v = (uint32_t)(uint16_t)bf16bits(sigf(go1) * tanhf2(c1n));
        st_u32_a(hdst + b * 1024 + sub * 16 + hcp, h0 | (h1v << 16));
      }
    }
    // ---- projection out_{tau-4} (all blocks: 5 cols x 4 batch rows) ----
    const bool pact = (tau >= 4);
    if (pact) {
      const __hip_bfloat16* h2s = h2buf + sl * 65536;           // h2_{tau-4}
      const __hip_bfloat16* xs  = Xbuf + (size_t)(tau - 4) * 65536;
      const int c0 = (bid & 15) * 5;
      const int b  = (bid >> 4) * 4 + (tid >> 7);
      const int kl = tid & 127;
      float pj[5];
      #pragma unroll
      for (int c = 0; c < 5; ++c) pj[c] = 0.f;
      // h2 rows from MALL: one 4-load batch (k2 = kl*2 + {0,256,512,768})
      uint32_t hreg[4];
      ld4_mall_s512(h2s + b * 1024 + kl * 2, hreg);
      #pragma unroll
      for (int i = 0; i < 4; ++i) {
        const int k2 = kl * 2 + i * 256;
        const float a0 = bflo(hreg[i]), a1 = bfhi(hreg[i]);
        #pragma unroll
        for (int c = 0; c < 5; ++c) {
          const uint32_t w = *(const uint32_t*)(WprojB + (c0 + c) * 1568 + k2);
          pj[c] += a0 * bflo(w) + a1 * bfhi(w);
        }
      }
      // X part (read-only, cached): k2 = kl*2 + {1024, 1280, (1536 if kl<16)}
      for (int k2 = kl * 2 + 1024; k2 < 1568; k2 += 256) {
        const uint32_t u = *(const uint32_t*)(xs + b * 1024 + (k2 - 768));
        const float a0 = bflo(u), a1 = bfhi(u);
        #pragma unroll
        for (int c = 0; c < 5; ++c) {
          const uint32_t w = *(const uint32_t*)(WprojB + (c0 + c) * 1568 + k2);
          pj[c] += a0 * bflo(w) + a1 * bfhi(w);
        }
      }
      #pragma unroll
      for (int c = 0; c < 5; ++c) {
        #pragma unroll
        for (int off = 32; off > 0; off >>= 1)
          pj[c] += __shfl_xor(pj[c], off, 64);
      }
      if (lane == 0) {
        #pragma unroll
        for (int c = 0; c < 5; ++c) sbuf[wave][c] = pj[c];
      }
    }
    __syncthreads();
    if (pact && ((wave & 1) == 0) && lane == 0) {
      const int c0 = (bid & 15) * 5;
      const int b  = (bid >> 4) * 4 + (wave >> 1);
      #pragma unroll
      for (int c = 0; c < 5; ++c)
        out[b * 48000 + (c0 + c) * 600 + (tau - 4)] =
            sbuf[wave][c] + sbuf[wave + 1][c] + bproj[c0 + c];
    }
    // ---- grid barrier: per-tau flag array; batched poll (1 RT per round) ---
    __syncthreads();   // drains vmcnt: this block's bypass stores complete
    if (tid == 0) st_u32_a(flags + (size_t)tau * 256 + bid, 1u);
    if (wave == 0) {
      const uint32_t* f = flags + (size_t)tau * 256 + lane;
      for (;;) {
        uint32_t a[4];
        ld4_flags(f, a);
        if (__all((int)(a[0] & a[1] & a[2] & a[3]))) break;
        __builtin_amdgcn_s_sleep(2);
      }
    }
    __syncthreads();
  }
}

// ---------------------------------------------------------------------------
extern "C" void kernel_launch(void* const* d_in, const int* in_sizes, int n_in,
                              void* d_out, int out_size, void* d_ws, size_t ws_size,
                              hipStream_t stream) {
  (void)in_sizes; (void)n_in; (void)out_size; (void)ws_size;
  const float* dur   = (const float*)d_in[0];   // [64][600][544]
  const float* dec   = (const float*)d_in[1];   // [64][80][600]
  const float* Wp1   = (const float*)d_in[3];
  const float* Wp2   = (const float*)d_in[4];
  const float* Wih1  = (const float*)d_in[5];
  const float* Whh1  = (const float*)d_in[6];
  const float* bih1  = (const float*)d_in[7];
  const float* bhh1  = (const float*)d_in[8];
  const float* Wih2  = (const float*)d_in[9];
  const float* Whh2  = (const float*)d_in[10];
  const float* bih2  = (const float*)d_in[11];
  const float* bhh2  = (const float*)d_in[12];
  const float* Wproj = (const float*)d_in[13];
  const float* bproj = (const float*)d_in[14];

  char* ws = (char*)d_ws;
  // layout:
  //   X    @ 0           : 600*64*1024*2 = 78,643,200
  //   WpjB @ 78,643,200  : 80*1568*2     =    250,880   -> ends 78,894,080
  //   comm @ 78,894,080  (memset to 0 AFTER prenet2; overlaps dead pn1):
  //     flags  +0          604*256*4 = 618,496          -> 618,496
  //     h1buf  +618,496    2 slots * 64*1024*2 = 262,144 -> 880,640
  //     h2buf  +880,640    262,144                      -> 1,142,784
  //     P0     +1,142,784  2 slots * 64*4096*2 = 1,048,576 -> 2,191,360
  //     P1     +2,191,360  1,048,576                    -> 3,239,936
  //   pn1  @ 78,894,080  : 39,321,600 (dead after prenet2; covers comm)
  __hip_bfloat16* X    = (__hip_bfloat16*)(ws + 0);
  __hip_bfloat16* WpjB = (__hip_bfloat16*)(ws + 78643200);
  char*           comm = ws + 78894080;
  uint32_t*       flags= (uint32_t*)(comm + 0);
  __hip_bfloat16* h1   = (__hip_bfloat16*)(comm + 618496);
  __hip_bfloat16* h2   = (__hip_bfloat16*)(comm + 880640);
  uint32_t*       P0   = (uint32_t*)(comm + 1142784);
  uint32_t*       P1   = (uint32_t*)(comm + 2191360);
  float*          pn1  = (float*)(ws + 78894080);

  prenet1_kernel<<<600, 256, 0, stream>>>(dec, Wp1, pn1);
  prenet2_kernel<<<dim3(600, 8), 256, 0, stream>>>(pn1, Wp2, X);
  // zero comm region (flags/h/P) after pn1 is consumed
  hipMemsetAsync(comm, 0, 3239936, stream);
  xfill_kernel<<<115200, 256, 0, stream>>>(dur, X);
  wprojcvt_kernel<<<490, 256, 0, stream>>>(Wproj, WpjB);
  persist_kernel<<<256, 512, 0, stream>>>(Wih1, Whh1, bih1, bhh1,
                                          Wih2, Whh2, bih2, bhh2,
                                          WpjB, bproj, X, P0, P1, h1, h2,
                                          flags, (float*)d_out);
}

// Round 4
// 5997.247 us; speedup vs baseline: 1.4813x; 1.4813x over previous
//
#include <hip/hip_runtime.h>
#include <hip/hip_bf16.h>
#include <stdint.h>

// ---------------------------------------------------------------------------
// Tacotron2 decoder on MI355X — persistent pipelined recurrence, v9.
// v9 = v8 + barrier/critical-path restructure:
//  (1) flag poll uses ONE dwordx4 per lane (64x16B vs 256x4B per wave):
//      the old poll was 65K same-line scalar transactions per round, a MALL
//      serialization storm and the prime suspect for the unexplained
//      ~9us/tick (v8: 14.2us/tick vs ~5us of accountable path).
//  (2) signal-early/poll-late: flag stored right after the consume-phase
//      drain; projection compute runs between signal and poll, so the poll
//      usually succeeds on round 1. Safe: proj h2 data is in registers
//      (issued at tick top, drained by the gemm-phase vmcnt/barriers).
//  (3) proj h2 loads issued at tick TOP (prev-tick data) — RT hidden.
//  (4) single-round K-reduction via pbuf4[4][..] (64KB LDS), consumers sum
//      4 partials in the original association order (bit-identical) —
//      removes 3 __syncthreads/tick.
// v8 history: 8578us persist (9279 -> 8883 total via issue-only P prefetch).
// ---------------------------------------------------------------------------

typedef short  bf16x8  __attribute__((ext_vector_type(8)));
typedef float  f32x16  __attribute__((ext_vector_type(16)));
typedef uint32_t u32x4 __attribute__((ext_vector_type(4)));

// ---------------- threefry2x32 (exact JAX semantics) ------------------------
__device__ __forceinline__ uint32_t rotl32(uint32_t x, int r) {
  return (x << r) | (x >> (32 - r));
}

__device__ __forceinline__ void tf2x32(uint32_t k0, uint32_t k1,
                                       uint32_t x0, uint32_t x1,
                                       uint32_t& o0, uint32_t& o1) {
  uint32_t k2 = k0 ^ k1 ^ 0x1BD11BDAu;
  x0 += k0; x1 += k1;
#define TF_R(r) { x0 += x1; x1 = rotl32(x1, r); x1 ^= x0; }
  TF_R(13) TF_R(15) TF_R(26) TF_R(6)   x0 += k1; x1 += k2 + 1u;
  TF_R(17) TF_R(29) TF_R(16) TF_R(24)  x0 += k2; x1 += k0 + 2u;
  TF_R(13) TF_R(15) TF_R(26) TF_R(6)   x0 += k0; x1 += k1 + 3u;
  TF_R(17) TF_R(29) TF_R(16) TF_R(24)  x0 += k1; x1 += k2 + 4u;
  TF_R(13) TF_R(15) TF_R(26) TF_R(6)   x0 += k2; x1 += k0 + 5u;
#undef TF_R
  o0 = x0; o1 = x1;
}

__device__ __forceinline__ void dropout_keys(uint32_t& a1, uint32_t& b1,
                                             uint32_t& a2, uint32_t& b2) {
  uint32_t o0, o1, p0, p1;
  tf2x32(0u, 42u, 0u, 2u, o0, o1);
  tf2x32(0u, 42u, 1u, 3u, p0, p1);
  a1 = o0; b1 = p0;
  a2 = o1; b2 = p1;
}

__device__ __forceinline__ bool keep_mask(uint32_t ka, uint32_t kb, uint32_t e) {
  const uint32_t H = 4923392u;       // (601*64*256)/2
  uint32_t o0, o1;
  if (e < H) { tf2x32(ka, kb, e, e + H, o0, o1); return o0 < 0x80000000u; }
  else       { tf2x32(ka, kb, e - H, e, o0, o1); return o1 < 0x80000000u; }
}

__device__ __forceinline__ float sigf(float x)  { return 1.f / (1.f + __expf(-x)); }
__device__ __forceinline__ float tanhf2(float x){ return 2.f / (1.f + __expf(-2.f * x)) - 1.f; }

__device__ __forceinline__ short bf16bits(float f) {
  __hip_bfloat16 h = __float2bfloat16(f);
  short s; __builtin_memcpy(&s, &h, 2);
  return s;
}
__device__ __forceinline__ float bflo(uint32_t u) {
  uint32_t x = u << 16; float f; __builtin_memcpy(&f, &x, 4); return f;
}
__device__ __forceinline__ float bfhi(uint32_t u) {
  uint32_t x = u & 0xffff0000u; float f; __builtin_memcpy(&f, &x, 4); return f;
}

// ---- relaxed agent-scope single-word accessors (flags only) ----------------
__device__ __forceinline__ void st_u32_a(void* p, uint32_t v) {
  __hip_atomic_store((uint32_t*)p, v, __ATOMIC_RELAXED, __HIP_MEMORY_SCOPE_AGENT);
}

// ---- BATCHED MALL loads: sc0 sc1 = bypass L1+L2, served at coherent MALL.
// N loads in flight, ONE s_waitcnt — ~1 round trip instead of N. -------------
__device__ __forceinline__ void ld8_mall(const __hip_bfloat16* p, bf16x8 (&d)[8]) {
  asm volatile(
      "global_load_dwordx4 %0, %8, off sc0 sc1\n\t"
      "global_load_dwordx4 %1, %8, off offset:32 sc0 sc1\n\t"
      "global_load_dwordx4 %2, %8, off offset:64 sc0 sc1\n\t"
      "global_load_dwordx4 %3, %8, off offset:96 sc0 sc1\n\t"
      "global_load_dwordx4 %4, %8, off offset:128 sc0 sc1\n\t"
      "global_load_dwordx4 %5, %8, off offset:160 sc0 sc1\n\t"
      "global_load_dwordx4 %6, %8, off offset:192 sc0 sc1\n\t"
      "global_load_dwordx4 %7, %8, off offset:224 sc0 sc1\n\t"
      "s_waitcnt vmcnt(0)"
      : "=&v"(d[0]), "=&v"(d[1]), "=&v"(d[2]), "=&v"(d[3]),
        "=&v"(d[4]), "=&v"(d[5]), "=&v"(d[6]), "=&v"(d[7])
      : "v"(p) : "memory");
}
// 4 independent addresses, ISSUE ONLY (no waitcnt): role-1/3 P-gate prefetch.
// Drains under the next ld8_mall vmcnt(0); consumer pins with ld4_pin().
__device__ __forceinline__ void ld4_mall4_issue(const uint32_t* p0, const uint32_t* p1,
                                                const uint32_t* p2, const uint32_t* p3,
                                                uint32_t (&d)[4]) {
  asm volatile(
      "global_load_dword %0, %4, off sc0 sc1\n\t"
      "global_load_dword %1, %5, off sc0 sc1\n\t"
      "global_load_dword %2, %6, off sc0 sc1\n\t"
      "global_load_dword %3, %7, off sc0 sc1"
      : "=&v"(d[0]), "=&v"(d[1]), "=&v"(d[2]), "=&v"(d[3])
      : "v"(p0), "v"(p1), "v"(p2), "v"(p3) : "memory");
}
// proj h2 rows at +0,+512,+1024,+1536 bytes — ISSUE ONLY (pin before use)
__device__ __forceinline__ void ld4_s512_issue(const __hip_bfloat16* p,
                                               uint32_t (&d)[4]) {
  asm volatile(
      "global_load_dword %0, %4, off sc0 sc1\n\t"
      "global_load_dword %1, %4, off offset:512 sc0 sc1\n\t"
      "global_load_dword %2, %4, off offset:1024 sc0 sc1\n\t"
      "global_load_dword %3, %4, off offset:1536 sc0 sc1"
      : "=&v"(d[0]), "=&v"(d[1]), "=&v"(d[2]), "=&v"(d[3])
      : "v"(p) : "memory");
}
// redefine 4 regs behind a vmcnt drain so no use can be hoisted above it
__device__ __forceinline__ void ld4_pin(uint32_t (&d)[4]) {
  asm volatile("s_waitcnt vmcnt(0)"
               : "+v"(d[0]), "+v"(d[1]), "+v"(d[2]), "+v"(d[3])
               :: "memory");
  __builtin_amdgcn_sched_barrier(0);
}
// barrier poll: ONE dwordx4 per lane (lane L covers flags 4L..4L+3)
__device__ __forceinline__ u32x4 ld_flags16(const uint32_t* p) {
  u32x4 d;
  asm volatile(
      "global_load_dwordx4 %0, %1, off sc0 sc1\n\t"
      "s_waitcnt vmcnt(0)"
      : "=&v"(d) : "v"(p) : "memory");
  return d;
}

// ---------------- prenet layer 1 --------------------------------------------
__global__ void prenet1_kernel(const float* __restrict__ dec,
                               const float* __restrict__ Wp1,
                               float* __restrict__ pn1) {
  const int t = blockIdx.x;
  const int tid = threadIdx.x;
  __shared__ float          sdec[64][81];
  __shared__ __hip_bfloat16 sw1[256][80];
  for (int idx = tid; idx < 64 * 80; idx += 256) {
    int b = idx / 80, m = idx - b * 80;
    sdec[b][m] = (t == 0) ? 0.f : dec[b * 48000 + m * 600 + (t - 1)];
  }
  for (int idx = tid; idx < 256 * 80; idx += 256) {
    int j = idx / 80, k = idx - j * 80;
    sw1[j][k] = __float2bfloat16(Wp1[idx]);
  }
  __syncthreads();
  uint32_t ka, kb, ka2, kb2;
  dropout_keys(ka, kb, ka2, kb2);
  const int b  = tid & 63;
  const int jg = tid >> 6;
  for (int jj = 0; jj < 64; ++jj) {
    const int j = jg * 64 + jj;
    float acc = 0.f;
    #pragma unroll
    for (int k = 0; k < 80; ++k)
      acc += sdec[b][k] * __bfloat162float(sw1[j][k]);
    const uint32_t e = (uint32_t)((t * 64 + b) * 256 + j);
    pn1[(t * 64 + b) * 256 + j] =
        keep_mask(ka, kb, e) ? 2.f * fmaxf(acc, 0.f) : 0.f;
  }
}

// ---------------- prenet layer 2 -> X[t][b][0..255] (bf16) ------------------
__global__ void prenet2_kernel(const float* __restrict__ pn1,
                               const float* __restrict__ Wp2,
                               __hip_bfloat16* __restrict__ X) {
  const int t  = blockIdx.x;
  const int j0 = blockIdx.y * 32;
  const int tid = threadIdx.x;
  __shared__ __hip_bfloat16 sact[64][258];
  __shared__ __hip_bfloat16 sw[32][256];
  for (int idx = tid; idx < 64 * 256; idx += 256) {
    int b = idx >> 8, k = idx & 255;
    sact[b][k] = __float2bfloat16(pn1[(t * 64 + b) * 256 + k]);
  }
  for (int idx = tid; idx < 32 * 256; idx += 256) {
    int r = idx >> 8, k = idx & 255;
    sw[r][k] = __float2bfloat16(Wp2[(j0 + r) * 256 + k]);
  }
  __syncthreads();
  uint32_t ka, kb, ka2, kb2;
  dropout_keys(ka, kb, ka2, kb2);
  const int b  = tid & 63;
  const int jg = tid >> 6;
  float acc[8];
  #pragma unroll
  for (int c = 0; c < 8; ++c) acc[c] = 0.f;
  for (int k = 0; k < 256; ++k) {
    const float a = __bfloat162float(sact[b][k]);
    #pragma unroll
    for (int c = 0; c < 8; ++c)
      acc[c] += a * __bfloat162float(sw[jg * 8 + c][k]);
  }
  #pragma unroll
  for (int c = 0; c < 8; ++c) {
    const int j = j0 + jg * 8 + c;
    const uint32_t e = (uint32_t)((t * 64 + b) * 256 + j);
    const float v = keep_mask(ka2, kb2, e) ? 2.f * fmaxf(acc[c], 0.f) : 0.f;
    X[(t * 64 + b) * 1024 + j] = __float2bfloat16(v);
  }
}

// ---------------- X[t][b][256..799] = dur[b][t][:], [800..1023] = 0 ---------
__global__ void xfill_kernel(const float* __restrict__ dur,
                             __hip_bfloat16* __restrict__ X) {
  const int idx = blockIdx.x * 256 + threadIdx.x;
  const int t  = idx / 49152;
  const int r  = idx - t * 49152;
  const int b  = r / 768;
  const int kk = r - b * 768;
  const float v = (kk < 544) ? dur[(b * 600 + t) * 544 + kk] : 0.f;
  X[(t * 64 + b) * 1024 + 256 + kk] = __float2bfloat16(v);
}

__global__ void wprojcvt_kernel(const float* __restrict__ W,
                                __hip_bfloat16* __restrict__ Wb) {
  const int idx = blockIdx.x * 256 + threadIdx.x;
  Wb[idx] = __float2bfloat16(W[idx]);
}

// ---------------- persistent pipelined recurrence ---------------------------
__launch_bounds__(512, 2)
__global__ void persist_kernel(
    const float* __restrict__ Wih1, const float* __restrict__ Whh1,
    const float* __restrict__ bih1, const float* __restrict__ bhh1,
    const float* __restrict__ Wih2, const float* __restrict__ Whh2,
    const float* __restrict__ bih2, const float* __restrict__ bhh2,
    const __hip_bfloat16* __restrict__ WprojB, const float* __restrict__ bproj,
    const __hip_bfloat16* __restrict__ Xbuf,
    uint32_t* __restrict__ P0, uint32_t* __restrict__ P1,     // bf16-pair rings
    __hip_bfloat16* __restrict__ h1buf, __hip_bfloat16* __restrict__ h2buf,
    uint32_t* __restrict__ flags,
    float* __restrict__ out) {
  const int bid  = blockIdx.x;
  const int role = bid >> 6;          // 0:AX 1:AF 2:B1 3:BF
  const int sub  = bid & 63;
  const int tid  = threadIdx.x;
  const int wave = tid >> 6;          // 8 waves
  const int lane = tid & 63;
  const int mh   = wave & 1;          // batch half
  const int kseg = wave >> 1;         // K quarter (256)

  __shared__ float pbuf4[4][2][32][64];  // per-kseg partial gates [seg][mh][m][n]
  __shared__ float sbuf[8][8];           // proj cross-wave partials

  // ---- persistent weight fragments (bf16, MFMA B layout) ----
  const float* Wsrc = (role == 0) ? Wih1 : (role == 1) ? Whh1
                    : (role == 2) ? Wih2 : Whh2;
  const int Ksrc  = (role == 0) ? 800 : 1024;
  const int nrow  = lane & 31;
  const int khalf = (lane >> 5) * 8;
  bf16x8 bfr[16][2];
  #pragma unroll
  for (int ks = 0; ks < 16; ++ks) {
    #pragma unroll
    for (int nt = 0; nt < 2; ++nt) {
      const int nloc = nt * 32 + nrow;
      const int g = (role == 1 || role == 3)
                  ? ((nloc >> 4) * 1024 + sub * 16 + (nloc & 15))  // i/f/g/o interleave
                  : (sub * 64 + nloc);                             // natural slice
      const int k0 = kseg * 256 + ks * 16 + khalf;
      bf16x8 v;
      if (k0 + 8 <= Ksrc) {
        const float* wp = Wsrc + (size_t)g * (size_t)Ksrc + k0;
        #pragma unroll
        for (int j = 0; j < 8; ++j) v[j] = bf16bits(wp[j]);
      } else {
        #pragma unroll
        for (int j = 0; j < 8; ++j) v[j] = (short)0;
      }
      bfr[ks][nt] = v;
    }
  }

  // ---- bias registers (role 0/2 write path): 8 consecutive gate cols ------
  float breg[8];
  if (role == 0 || role == 2) {
    const float* bi = (role == 0) ? bih1 : bih2;
    const float* bh = (role == 0) ? bhh1 : bhh2;
    const int c0 = (tid * 8) & 63;
    #pragma unroll
    for (int j = 0; j < 8; ++j) {
      const int g = sub * 64 + c0 + j;
      breg[j] = bi[g] + bh[g];
    }
  }

  float cst[2] = {0.f, 0.f};          // c-state: (b = tid>>3, cols hcp, hcp+1)
  const int brow = mh * 32 + (lane & 31);
  // proj decomposition constants (loop-invariant)
  const int c0p = (bid & 15) * 5;
  const int bp  = (bid >> 4) * 4 + (tid >> 7);
  const int kl  = tid & 127;

  for (int tau = 0; tau < 604; ++tau) {
    const int sl = tau & 1;
    const bool active =
        (role == 0) ? (tau <= 599) :
        (role == 1) ? (tau >= 1 && tau <= 600) :
        (role == 2) ? (tau >= 2 && tau <= 601) :
                      (tau >= 3 && tau <= 602);
    const bool pact = (tau >= 4);

    // ---- (3) issue proj h2 loads at tick TOP (prev-tick data, ready) ----
    uint32_t hreg[4];
    if (pact) {
      ld4_s512_issue(h2buf + sl * 65536 + bp * 1024 + kl * 2, hreg);
    }

    f32x16 acc0, acc1;
    #pragma unroll
    for (int i = 0; i < 16; ++i) { acc0[i] = 0.f; acc1[i] = 0.f; }

    uint32_t pg4[4] = {0u, 0u, 0u, 0u};   // prefetched P gate pairs (roles 1/3)

    if (active) {
      if (role == 0) {
        // X is read-only input: plain cached loads
        const bf16x8* ap = reinterpret_cast<const bf16x8*>(
            Xbuf + (size_t)tau * 65536 + brow * 1024 + kseg * 256 + khalf);
        #pragma unroll
        for (int ks = 0; ks < 16; ++ks) {
          const bf16x8 a = ap[ks * 2];
          acc0 = __builtin_amdgcn_mfma_f32_32x32x16_bf16(a, bfr[ks][0], acc0, 0, 0, 0);
          acc1 = __builtin_amdgcn_mfma_f32_32x32x16_bf16(a, bfr[ks][1], acc1, 0, 0, 0);
        }
      } else {
        // P-gate prefetch (roles 1/3): ISSUE ONLY — drains under the h-ring
        // ld8_mall vmcnt(0) below (one MALL round trip covers all).
        if (role & 1) {
          const uint32_t* Psrc = ((role == 1) ? P0 : P1) + ((tau + 1) & 1) * 131072;
          const int hcp = (tid & 7) * 2;
          const int pb  = tid >> 3;
          const uint32_t* q = Psrc + ((pb * 4096 + sub * 16 + hcp) >> 1);
          ld4_mall4_issue(q, q + 512, q + 1024, q + 1536, pg4);
        }
        // h ring (cross-block comm) — two 8-load batches from MALL
        const __hip_bfloat16* Asrc =
            ((role == 3) ? h2buf : h1buf) + sl * 65536;
        const __hip_bfloat16* abase = Asrc + brow * 1024 + kseg * 256 + khalf;
        bf16x8 A[8];
        ld8_mall(abase, A);
        #pragma unroll
        for (int ks = 0; ks < 8; ++ks) {
          acc0 = __builtin_amdgcn_mfma_f32_32x32x16_bf16(A[ks], bfr[ks][0], acc0, 0, 0, 0);
          acc1 = __builtin_amdgcn_mfma_f32_32x32x16_bf16(A[ks], bfr[ks][1], acc1, 0, 0, 0);
        }
        ld8_mall(abase + 128, A);   // +256 B: ks 8..15
        #pragma unroll
        for (int ks = 0; ks < 8; ++ks) {
          acc0 = __builtin_amdgcn_mfma_f32_32x32x16_bf16(A[ks], bfr[ks + 8][0], acc0, 0, 0, 0);
          acc1 = __builtin_amdgcn_mfma_f32_32x32x16_bf16(A[ks], bfr[ks + 8][1], acc1, 0, 0, 0);
        }
      }
    }
    // ---- (4) single-round K-split reduction: each kseg writes its plane ----
    if (active) {
      #pragma unroll
      for (int reg = 0; reg < 16; ++reg) {
        const int mrow = (reg & 3) + 8 * (reg >> 2) + 4 * (lane >> 5);
        const int col  = lane & 31;
        pbuf4[kseg][mh][mrow][col]      = acc0[reg];
        pbuf4[kseg][mh][mrow][col + 32] = acc1[reg];
      }
    }
    __syncthreads();
    // ---- consume (sum 4 kseg planes in original association order) ----
    if (active) {
      if (role == 0 || role == 2) {   // write P ring (bf16 pairs, bypass)
        uint32_t* Pd = ((role == 0) ? P0 : P1) + sl * 131072;
        const int i0 = tid * 8;
        const int b  = i0 >> 6;
        const int c0 = i0 & 63;
        uint32_t* dst = Pd + ((b * 4096 + sub * 64 + c0) >> 1);
        const int m = b & 31, mb = b >> 5;
        const float* q0 = &pbuf4[0][mb][m][0];
        const float* q1 = &pbuf4[1][mb][m][0];
        const float* q2 = &pbuf4[2][mb][m][0];
        const float* q3 = &pbuf4[3][mb][m][0];
        #pragma unroll
        for (int j = 0; j < 4; ++j) {
          const int ca = c0 + 2 * j, cb = c0 + 2 * j + 1;
          const float va = ((q0[ca] + q1[ca]) + q2[ca]) + q3[ca] + breg[2 * j];
          const float vb = ((q0[cb] + q1[cb]) + q2[cb]) + q3[cb] + breg[2 * j + 1];
          const uint32_t lo = (uint32_t)(uint16_t)bf16bits(va);
          const uint32_t hi = (uint32_t)(uint16_t)bf16bits(vb);
          st_u32_a(dst + j, lo | (hi << 16));
        }
      } else {                        // LSTM pointwise with prefetched gates
        ld4_pin(pg4);                 // free here (drained by ld8/vmcnt + barrier)
        __hip_bfloat16* hdst =
            ((role == 1) ? h1buf : h2buf) + ((tau + 1) & 1) * 65536;
        const int hcp = (tid & 7) * 2;
        const int b   = tid >> 3;
        const int m = b & 31, mb = b >> 5;
        const float* q0 = &pbuf4[0][mb][m][0];
        const float* q1 = &pbuf4[1][mb][m][0];
        const float* q2 = &pbuf4[2][mb][m][0];
        const float* q3 = &pbuf4[3][mb][m][0];
#define SUM4(idx) ((((q0[idx] + q1[idx]) + q2[idx]) + q3[idx]))
        const float gi0 = SUM4(hcp)      + bflo(pg4[0]), gi1 = SUM4(hcp + 1)      + bfhi(pg4[0]);
        const float gf0 = SUM4(16 + hcp) + bflo(pg4[1]), gf1 = SUM4(16 + hcp + 1) + bfhi(pg4[1]);
        const float gg0 = SUM4(32 + hcp) + bflo(pg4[2]), gg1 = SUM4(32 + hcp + 1) + bfhi(pg4[2]);
        const float go0 = SUM4(48 + hcp) + bflo(pg4[3]), go1 = SUM4(48 + hcp + 1) + bfhi(pg4[3]);
#undef SUM4
        const float c0n = sigf(gf0) * cst[0] + sigf(gi0) * tanhf2(gg0);
        const float c1n = sigf(gf1) * cst[1] + sigf(gi1) * tanhf2(gg1);
        cst[0] = c0n; cst[1] = c1n;
        const uint32_t h0 = (uint32_t)(uint16_t)bf16bits(sigf(go0) * tanhf2(c0n));
        const uint32_t h1v = (uint32_t)(uint16_t)bf16bits(sigf(go1) * tanhf2(c1n));
        st_u32_a(hdst + b * 1024 + sub * 16 + hcp, h0 | (h1v << 16));
      }
    }
    // ---- (2) signal EARLY: drain this block's bypass stores, set flag ----
    __syncthreads();   // per-wave vmcnt(0) before barrier => all stores done
    if (tid == 0) st_u32_a(flags + (size_t)tau * 256 + bid, 1u);

    // ---- projection out_{tau-4} runs BETWEEN signal and poll ----
    if (pact) {
      ld4_pin(hreg);   // data long since arrived; pin against hoisting
      const __hip_bfloat16* xs = Xbuf + (size_t)(tau - 4) * 65536;
      float pj[5];
      #pragma unroll
      for (int c = 0; c < 5; ++c) pj[c] = 0.f;
      #pragma unroll
      for (int i = 0; i < 4; ++i) {
        const int k2 = kl * 2 + i * 256;
        const float a0 = bflo(hreg[i]), a1 = bfhi(hreg[i]);
        #pragma unroll
        for (int c = 0; c < 5; ++c) {
          const uint32_t w = *(const uint32_t*)(WprojB + (c0p + c) * 1568 + k2);
          pj[c] += a0 * bflo(w) + a1 * bfhi(w);
        }
      }
      // X part (read-only, cached): k2 = kl*2 + {1024, 1280, (1536 if kl<16)}
      for (int k2 = kl * 2 + 1024; k2 < 1568; k2 += 256) {
        const uint32_t u = *(const uint32_t*)(xs + bp * 1024 + (k2 - 768));
        const float a0 = bflo(u), a1 = bfhi(u);
        #pragma unroll
        for (int c = 0; c < 5; ++c) {
          const uint32_t w = *(const uint32_t*)(WprojB + (c0p + c) * 1568 + k2);
          pj[c] += a0 * bflo(w) + a1 * bfhi(w);
        }
      }
      #pragma unroll
      for (int c = 0; c < 5; ++c) {
        #pragma unroll
        for (int off = 32; off > 0; off >>= 1)
          pj[c] += __shfl_xor(pj[c], off, 64);
      }
      if (lane == 0) {
        #pragma unroll
        for (int c = 0; c < 5; ++c) sbuf[wave][c] = pj[c];
      }
    }
    __syncthreads();
    if (pact && ((wave & 1) == 0) && lane == 0) {
      const int b = (bid >> 4) * 4 + (wave >> 1);
      #pragma unroll
      for (int c = 0; c < 5; ++c)
        out[b * 48000 + (c0p + c) * 600 + (tau - 4)] =
            sbuf[wave][c] + sbuf[wave + 1][c] + bproj[c0p + c];
    }
    // ---- (1) poll LATE with one dwordx4 per lane (4x fewer transactions) ---
    if (wave == 0) {
      const uint32_t* f = flags + (size_t)tau * 256 + lane * 4;
      for (;;) {
        u32x4 a = ld_flags16(f);
        if (__all((int)(a[0] & a[1] & a[2] & a[3]))) break;
        __builtin_amdgcn_s_sleep(2);
      }
    }
    __syncthreads();
  }
}

// ---------------------------------------------------------------------------
extern "C" void kernel_launch(void* const* d_in, const int* in_sizes, int n_in,
                              void* d_out, int out_size, void* d_ws, size_t ws_size,
                              hipStream_t stream) {
  (void)in_sizes; (void)n_in; (void)out_size; (void)ws_size;
  const float* dur   = (const float*)d_in[0];   // [64][600][544]
  const float* dec   = (const float*)d_in[1];   // [64][80][600]
  const float* Wp1   = (const float*)d_in[3];
  const float* Wp2   = (const float*)d_in[4];
  const float* Wih1  = (const float*)d_in[5];
  const float* Whh1  = (const float*)d_in[6];
  const float* bih1  = (const float*)d_in[7];
  const float* bhh1  = (const float*)d_in[8];
  const float* Wih2  = (const float*)d_in[9];
  const float* Whh2  = (const float*)d_in[10];
  const float* bih2  = (const float*)d_in[11];
  const float* bhh2  = (const float*)d_in[12];
  const float* Wproj = (const float*)d_in[13];
  const float* bproj = (const float*)d_in[14];

  char* ws = (char*)d_ws;
  // layout:
  //   X    @ 0           : 600*64*1024*2 = 78,643,200
  //   WpjB @ 78,643,200  : 80*1568*2     =    250,880   -> ends 78,894,080
  //   comm @ 78,894,080  (memset to 0 AFTER prenet2; overlaps dead pn1):
  //     flags  +0          604*256*4 = 618,496          -> 618,496
  //     h1buf  +618,496    2 slots * 64*1024*2 = 262,144 -> 880,640
  //     h2buf  +880,640    262,144                      -> 1,142,784
  //     P0     +1,142,784  2 slots * 64*4096*2 = 1,048,576 -> 2,191,360
  //     P1     +2,191,360  1,048,576                    -> 3,239,936
  //   pn1  @ 78,894,080  : 39,321,600 (dead after prenet2; covers comm)
  __hip_bfloat16* X    = (__hip_bfloat16*)(ws + 0);
  __hip_bfloat16* WpjB = (__hip_bfloat16*)(ws + 78643200);
  char*           comm = ws + 78894080;
  uint32_t*       flags= (uint32_t*)(comm + 0);
  __hip_bfloat16* h1   = (__hip_bfloat16*)(comm + 618496);
  __hip_bfloat16* h2   = (__hip_bfloat16*)(comm + 880640);
  uint32_t*       P0   = (uint32_t*)(comm + 1142784);
  uint32_t*       P1   = (uint32_t*)(comm + 2191360);
  float*          pn1  = (float*)(ws + 78894080);

  prenet1_kernel<<<600, 256, 0, stream>>>(dec, Wp1, pn1);
  prenet2_kernel<<<dim3(600, 8), 256, 0, stream>>>(pn1, Wp2, X);
  // zero comm region (flags/h/P) after pn1 is consumed
  hipMemsetAsync(comm, 0, 3239936, stream);
  xfill_kernel<<<115200, 256, 0, stream>>>(dur, X);
  wprojcvt_kernel<<<490, 256, 0, stream>>>(Wproj, WpjB);
  persist_kernel<<<256, 512, 0, stream>>>(Wih1, Whh1, bih1, bhh1,
                                          Wih2, Whh2, bih2, bhh2,
                                          WpjB, bproj, X, P0, P1, h1, h2,
                                          flags, (float*)d_out);
}